// Round 6
// baseline (2639.985 us; speedup 1.0000x reference)
//
#include <hip/hip_runtime.h>

// ---------------- problem constants ----------------
constexpr int B = 64, L = 512, E = 256, H = 512;
constexpr int ROWS = 4 * H;      // 2048 gate-rows (unit*4 + gate interleave)
constexpr int K    = E + H;      // 768
constexpr int K4   = K / 4;      // 192

// ---------------- ws layout (in floats) ----------------
constexpr size_t OFF_WT4   = 0;
constexpr size_t SZ_WT4    = (size_t)K4 * ROWS * 4;     // float4[K4][ROWS]
constexpr size_t OFF_BI    = OFF_WT4 + SZ_WT4;          // interleaved biases [ROWS]
constexpr size_t SZ_BI     = ROWS;
constexpr size_t OFF_H2    = OFF_BI + SZ_BI;            // TAGGED h dbuf [2][B][H] x (val,tag)
constexpr size_t SZ_H2     = (size_t)2 * B * H * 2;     // in floats (u64 per element)
constexpr size_t OFF_REP   = OFF_H2 + SZ_H2;            // rep accumulator [B][H]
constexpr size_t SZ_REP    = (size_t)B * H;
constexpr size_t WS_FLOATS = OFF_REP + SZ_REP;

// ---------------- prep: transpose + interleave weights, invalidate h tags ----------------
__global__ __launch_bounds__(256) void prep_weights(
    const float* __restrict__ Wf, const float* __restrict__ Wi,
    const float* __restrict__ Wc, const float* __restrict__ Wo,
    const float* __restrict__ bf, const float* __restrict__ bi,
    const float* __restrict__ bc, const float* __restrict__ bo,
    float* __restrict__ ws)
{
    float* WT4 = ws + OFF_WT4;
    float* bI  = ws + OFF_BI;
    int idx = blockIdx.x * 256 + threadIdx.x;            // 65536 threads
    const float* Ws[4] = {Wf, Wi, Wc, Wo};
    #pragma unroll
    for (int j = 0; j < 6; ++j) {
        int item = idx + j * 65536;                      // [0, 393216)
        int k4   = item >> 11;                           // /2048
        int row  = item & 2047;
        int unit = row >> 2, gate = row & 3;
        const float* W = Ws[gate];
        float4 v = *(const float4*)(W + (size_t)unit * K + (size_t)k4 * 4);
        *(float4*)(WT4 + ((size_t)k4 * ROWS + row) * 4) = v;
    }
    if (idx < ROWS) {
        int unit = idx >> 2, gate = idx & 3;
        const float* bs[4] = {bf, bi, bc, bo};
        bI[idx] = bs[gate][unit];
    }
    // zero all tags (tag 0 matches no want >= 2); end-of-dispatch L2 writeback makes
    // these visible to persist's sc-bypass loads (validated R2..R5).
    ((unsigned long long*)(ws + OFF_H2))[idx] = 0ull;    // 2*B*H = 65536 u64 exactly
}

// ---------------- persistent LSTM kernel ----------------
// grid 256 = 32 row-groups x 8 seq-groups; bid = rg*8 + sg.
// block 256 thr = 4 waves; wave w, lane l: q = l>>4, rl = l&15, m = w*4+q (0..15).
//
// R6 RESTRUCTURE (latency-pipelining): each step is split into two seq-group
// half-steps, A = seqs 0..3 and B = seqs 4..7. The tagged LLC round trip for
// each half hides under the OTHER half's GEMV+reduce:
//   [hvA issued at end of prev step] E-GEMV A | verify A | stage A | S1a |
//   issue hvB | H-GEMV A | S2a | reduce A + store h_A(t+1) |
//   E-GEMV B | verify B | stage B | land emb | S1b | H-GEMV B | S2b |
//   reduce B + store h_B(t+1) | issue hvA(t+1)
// LDS hazards: S2a separates H-GEMV-A reads of h_lds from stage-B writes;
// S1b separates reduce-A reads of part2 from partial-B writes; S2b separates
// H-GEMV-B reads from next step's stage-A writes. (Each reuse crosses >=1 barrier.)
//
// GEMV geometry (R4/R5-validated LDS return-bus model): 4 rows/lane x 12 k4 —
// one ds_read_b128 broadcast feeds 16 FMAs.
// REGISTER RULE (R1 failure): weights live in ONE wreg[48] float4 array with
// constant indices (E=[0..15], H=[16..47]) -> AGPR promotion; never split it.
//
// Cross-block protocol = tagged scheme (R3..R5): each h element is an 8-byte
// atomic (f32 value, u32 tag); producers store (h, t+2) with one relaxed
// agent-scope store; consumers' staging load IS the poll. WAR on the dbuf:
// per-half all-gather bounds inter-block skew < 1 step (same induction, and
// tags self-detect staleness).
__global__ __launch_bounds__(256, 1) void lstm_persist(
    float* __restrict__ ws,
    const int* __restrict__ x, const int* __restrict__ mask,
    const float* __restrict__ embed)
{
    __shared__ float emb_lds[2][8][E];                   // 16 KB dbuf (local gather)
    __shared__ float h_lds[4 * H];                       // 8 KB (per-half staging)
    __shared__ float part2_lds[4 * 16 * 64];             // 16 KB: [s8h][m][row]

    const int bid = blockIdx.x;
    const int rg  = bid >> 3, sg = bid & 7;
    const int tid = threadIdx.x;
    const int w   = tid >> 6, l = tid & 63;
    const int q   = l >> 4, rl = l & 15, m = w * 4 + q;  // GEMV mapping
    const int seq_base = sg * 8;
    const int gate = l & 3, qlane = l >> 2;              // reduce: lane l owns row rg*64+l

    const float4* WT4 = (const float4*)(ws + OFF_WT4);
    const float*  bI  = ws + OFF_BI;
    unsigned long long* h2 = (unsigned long long*)(ws + OFF_H2);
    float* repg = ws + OFF_REP;

    // ---- stationary weights: ONE array, const indices (AGPR promotion!)
    float4 wreg[48];
    {
        const int rowA = rg * 64 + rl * 4;
        #pragma unroll
        for (int jj = 0; jj < 4; ++jj)
            #pragma unroll
            for (int r = 0; r < 4; ++r)
                wreg[r * 4 + jj] = WT4[(size_t)(w * 16 + q + 4 * jj) * ROWS + rowA + r];
        #pragma unroll
        for (int jj = 0; jj < 8; ++jj)
            #pragma unroll
            for (int r = 0; r < 4; ++r)
                wreg[16 + r * 8 + jj] = WT4[(size_t)(64 + w * 32 + q + 4 * jj) * ROWS + rowA + r];
    }
    const float breg = bI[rg * 64 + l];                  // bias for the REDUCE row

    // ---- per-owner-lane state (gate==0 lanes): half A -> (c0,h0,r0), B -> (c1,h1,r1)
    float c0 = 0.f, c1 = 0.f, h0 = 0.f, h1 = 0.f, r0 = 0.f, r1 = 0.f;

    const int sl = tid >> 5, col = (tid & 31) * 8;       // emb gather mapping

    // ---- prologue: local emb gather for t=0; h_lds = 0 (used by both halves at t=0)
    {
        int tok = x[(size_t)(seq_base + sl) * L + 0];
        const float* er = embed + (size_t)tok * E + col;
        *(float4*)&emb_lds[0][sl][col]     = *(const float4*)er;
        *(float4*)&emb_lds[0][sl][col + 4] = *(const float4*)(er + 4);
        #pragma unroll
        for (int i = 0; i < 8; ++i) h_lds[tid + i * 256] = 0.f;
    }
    __syncthreads();

    unsigned long long hvA[8], hvB[8];

    for (int t = 0; t < L; ++t) {
        const int cur = t & 1, nxt = cur ^ 1;
        const unsigned long long* c2c = h2 + (size_t)cur * B * H + (size_t)seq_base * H;
        unsigned long long*       c2n = h2 + (size_t)nxt * B * H + (size_t)seq_base * H;

        // emb prefetch for t+1 (plain cached loads, read-only data)
        float4 e0, e1;
        const bool pf = (t + 1) < L;
        if (pf) {
            int tok = x[(size_t)(seq_base + sl) * L + (t + 1)];
            const float* er = embed + (size_t)tok * E + col;
            e0 = *(const float4*)er;
            e1 = *(const float4*)(er + 4);
        }

        // ================= HALF A (seqs 0..3) =================
        float acc[4][4];
        #pragma unroll
        for (int r = 0; r < 4; ++r)
            #pragma unroll
            for (int s8h = 0; s8h < 4; ++s8h) acc[r][s8h] = 0.f;

        // E-GEMV A (no h dependency -> covers hvA's LLC round trip)
        #pragma unroll
        for (int jj = 0; jj < 4; ++jj) {
            const int off = (w * 16 + q + 4 * jj) * 4;
            #pragma unroll
            for (int s8h = 0; s8h < 4; ++s8h) {
                float4 c4 = *(const float4*)&emb_lds[cur][s8h][off];
                #pragma unroll
                for (int r = 0; r < 4; ++r) {
                    float4 wv = wreg[r * 4 + jj];
                    acc[r][s8h] = fmaf(wv.x, c4.x, acc[r][s8h]);
                    acc[r][s8h] = fmaf(wv.y, c4.y, acc[r][s8h]);
                    acc[r][s8h] = fmaf(wv.z, c4.z, acc[r][s8h]);
                    acc[r][s8h] = fmaf(wv.w, c4.w, acc[r][s8h]);
                }
            }
        }

        if (t > 0) {
            // verify hvA (issued at end of previous step), retry = reload
            const unsigned int want = (unsigned int)(t + 1);
            int guard = 0;
            for (;;) {
                bool ok = true;
                #pragma unroll
                for (int i = 0; i < 8; ++i)
                    ok &= ((unsigned int)(hvA[i] >> 32) == want);
                if (__all(ok) || ++guard > (1 << 20)) break;
                __builtin_amdgcn_s_sleep(2);
                #pragma unroll
                for (int i = 0; i < 4; ++i) {
                    hvA[2 * i]     = __hip_atomic_load(&c2c[i * 512 + tid * 2],
                                        __ATOMIC_RELAXED, __HIP_MEMORY_SCOPE_AGENT);
                    hvA[2 * i + 1] = __hip_atomic_load(&c2c[i * 512 + tid * 2 + 1],
                                        __ATOMIC_RELAXED, __HIP_MEMORY_SCOPE_AGENT);
                }
            }
            #pragma unroll
            for (int i = 0; i < 4; ++i)
                *(float2*)&h_lds[i * 512 + tid * 2] = make_float2(
                    __uint_as_float((unsigned int)hvA[2 * i]),
                    __uint_as_float((unsigned int)hvA[2 * i + 1]));
            // issue hvB now -> flies under S1a + H-GEMV A (+ reduce A + E-GEMV B)
            #pragma unroll
            for (int i = 0; i < 4; ++i) {
                hvB[2 * i]     = __hip_atomic_load(&c2c[2048 + i * 512 + tid * 2],
                                    __ATOMIC_RELAXED, __HIP_MEMORY_SCOPE_AGENT);
                hvB[2 * i + 1] = __hip_atomic_load(&c2c[2048 + i * 512 + tid * 2 + 1],
                                    __ATOMIC_RELAXED, __HIP_MEMORY_SCOPE_AGENT);
            }
        }
        __syncthreads();                                 // S1a: h_lds(A) ready

        // H-GEMV A
        #pragma unroll
        for (int jj = 0; jj < 8; ++jj) {
            const int off = (w * 32 + q + 4 * jj) * 4;
            #pragma unroll
            for (int s8h = 0; s8h < 4; ++s8h) {
                float4 c4 = *(const float4*)&h_lds[s8h * 512 + off];
                #pragma unroll
                for (int r = 0; r < 4; ++r) {
                    float4 wv = wreg[16 + r * 8 + jj];
                    acc[r][s8h] = fmaf(wv.x, c4.x, acc[r][s8h]);
                    acc[r][s8h] = fmaf(wv.y, c4.y, acc[r][s8h]);
                    acc[r][s8h] = fmaf(wv.z, c4.z, acc[r][s8h]);
                    acc[r][s8h] = fmaf(wv.w, c4.w, acc[r][s8h]);
                }
            }
        }
        #pragma unroll
        for (int s8h = 0; s8h < 4; ++s8h) {
            float4 v = make_float4(acc[0][s8h], acc[1][s8h], acc[2][s8h], acc[3][s8h]);
            *(float4*)&part2_lds[(s8h * 16 + m) * 64 + rl * 4] = v;
        }
        __syncthreads();                                 // S2a (also fences h_lds reuse)

        // reduce A: wave w owns seq (seq_base + w); store h_A(t+1) tagged
        {
            float a = breg;
            #pragma unroll
            for (int mm = 0; mm < 16; ++mm)
                a += part2_lds[(w * 16 + mm) * 64 + l];
            float act = (gate == 2) ? tanhf(a) : 1.f / (1.f + expf(-a));
            int ab = __float_as_int(act);
            float fg = __int_as_float(__builtin_amdgcn_mov_dpp(ab, 0x00, 0xF, 0xF, true));
            float ig = __int_as_float(__builtin_amdgcn_mov_dpp(ab, 0x55, 0xF, 0xF, true));
            float cg = __int_as_float(__builtin_amdgcn_mov_dpp(ab, 0xAA, 0xF, 0xF, true));
            float og = __int_as_float(__builtin_amdgcn_mov_dpp(ab, 0xFF, 0xF, 0xF, true));
            if (gate == 0) {
                c0 = fg * c0 + ig * cg;                  // c not mask-blended (matches ref)
                float hn = og * tanhf(c0);
                int seq = seq_base + w;
                float mk = (mask[(size_t)seq * L + t] != 0) ? 1.f : 0.f;
                float h = hn * mk + h0 * (1.f - mk);
                h0 = h;
                unsigned long long p64 = (((unsigned long long)(unsigned int)(t + 2)) << 32)
                                       | (unsigned long long)__float_as_uint(h);
                __hip_atomic_store(&c2n[(size_t)w * H + rg * 16 + qlane],
                                   p64, __ATOMIC_RELAXED, __HIP_MEMORY_SCOPE_AGENT);
                r0 += h * mk;
            }
        }

        // ================= HALF B (seqs 4..7) =================
        #pragma unroll
        for (int r = 0; r < 4; ++r)
            #pragma unroll
            for (int s8h = 0; s8h < 4; ++s8h) acc[r][s8h] = 0.f;

        // E-GEMV B (covers the tail of hvB's flight + half-A store RT)
        #pragma unroll
        for (int jj = 0; jj < 4; ++jj) {
            const int off = (w * 16 + q + 4 * jj) * 4;
            #pragma unroll
            for (int s8h = 0; s8h < 4; ++s8h) {
                float4 c4 = *(const float4*)&emb_lds[cur][4 + s8h][off];
                #pragma unroll
                for (int r = 0; r < 4; ++r) {
                    float4 wv = wreg[r * 4 + jj];
                    acc[r][s8h] = fmaf(wv.x, c4.x, acc[r][s8h]);
                    acc[r][s8h] = fmaf(wv.y, c4.y, acc[r][s8h]);
                    acc[r][s8h] = fmaf(wv.z, c4.z, acc[r][s8h]);
                    acc[r][s8h] = fmaf(wv.w, c4.w, acc[r][s8h]);
                }
            }
        }

        if (t > 0) {
            const unsigned int want = (unsigned int)(t + 1);
            int guard = 0;
            for (;;) {
                bool ok = true;
                #pragma unroll
                for (int i = 0; i < 8; ++i)
                    ok &= ((unsigned int)(hvB[i] >> 32) == want);
                if (__all(ok) || ++guard > (1 << 20)) break;
                __builtin_amdgcn_s_sleep(2);
                #pragma unroll
                for (int i = 0; i < 4; ++i) {
                    hvB[2 * i]     = __hip_atomic_load(&c2c[2048 + i * 512 + tid * 2],
                                        __ATOMIC_RELAXED, __HIP_MEMORY_SCOPE_AGENT);
                    hvB[2 * i + 1] = __hip_atomic_load(&c2c[2048 + i * 512 + tid * 2 + 1],
                                        __ATOMIC_RELAXED, __HIP_MEMORY_SCOPE_AGENT);
                }
            }
            #pragma unroll
            for (int i = 0; i < 4; ++i)
                *(float2*)&h_lds[i * 512 + tid * 2] = make_float2(
                    __uint_as_float((unsigned int)hvB[2 * i]),
                    __uint_as_float((unsigned int)hvB[2 * i + 1]));
        }
        // land emb prefetch (into the OTHER emb buffer; read after S1b+S2b)
        if (pf) {
            *(float4*)&emb_lds[nxt][sl][col]     = e0;
            *(float4*)&emb_lds[nxt][sl][col + 4] = e1;
        }
        __syncthreads();                                 // S1b: h_lds(B) ready

        // H-GEMV B
        #pragma unroll
        for (int jj = 0; jj < 8; ++jj) {
            const int off = (w * 32 + q + 4 * jj) * 4;
            #pragma unroll
            for (int s8h = 0; s8h < 4; ++s8h) {
                float4 c4 = *(const float4*)&h_lds[s8h * 512 + off];
                #pragma unroll
                for (int r = 0; r < 4; ++r) {
                    float4 wv = wreg[16 + r * 8 + jj];
                    acc[r][s8h] = fmaf(wv.x, c4.x, acc[r][s8h]);
                    acc[r][s8h] = fmaf(wv.y, c4.y, acc[r][s8h]);
                    acc[r][s8h] = fmaf(wv.z, c4.z, acc[r][s8h]);
                    acc[r][s8h] = fmaf(wv.w, c4.w, acc[r][s8h]);
                }
            }
        }
        #pragma unroll
        for (int s8h = 0; s8h < 4; ++s8h) {
            float4 v = make_float4(acc[0][s8h], acc[1][s8h], acc[2][s8h], acc[3][s8h]);
            *(float4*)&part2_lds[(s8h * 16 + m) * 64 + rl * 4] = v;
        }
        __syncthreads();                                 // S2b (also fences h_lds reuse)

        // reduce B: wave w owns seq (seq_base + 4 + w); store h_B(t+1) tagged
        {
            float a = breg;
            #pragma unroll
            for (int mm = 0; mm < 16; ++mm)
                a += part2_lds[(w * 16 + mm) * 64 + l];
            float act = (gate == 2) ? tanhf(a) : 1.f / (1.f + expf(-a));
            int ab = __float_as_int(act);
            float fg = __int_as_float(__builtin_amdgcn_mov_dpp(ab, 0x00, 0xF, 0xF, true));
            float ig = __int_as_float(__builtin_amdgcn_mov_dpp(ab, 0x55, 0xF, 0xF, true));
            float cg = __int_as_float(__builtin_amdgcn_mov_dpp(ab, 0xAA, 0xF, 0xF, true));
            float og = __int_as_float(__builtin_amdgcn_mov_dpp(ab, 0xFF, 0xF, 0xF, true));
            if (gate == 0) {
                c1 = fg * c1 + ig * cg;
                float hn = og * tanhf(c1);
                int seq = seq_base + 4 + w;
                float mk = (mask[(size_t)seq * L + t] != 0) ? 1.f : 0.f;
                float h = hn * mk + h1 * (1.f - mk);
                h1 = h;
                unsigned long long p64 = (((unsigned long long)(unsigned int)(t + 2)) << 32)
                                       | (unsigned long long)__float_as_uint(h);
                __hip_atomic_store(&c2n[(size_t)(4 + w) * H + rg * 16 + qlane],
                                   p64, __ATOMIC_RELAXED, __HIP_MEMORY_SCOPE_AGENT);
                r1 += h * mk;
            }
        }

        // issue hvA for step t+1 (producers' h_A(t+1) stores happened a half-step
        // ago; stale tags are handled by the verify-retry at the top of t+1)
        if (pf) {
            const unsigned long long* c2x = h2 + (size_t)nxt * B * H + (size_t)seq_base * H;
            #pragma unroll
            for (int i = 0; i < 4; ++i) {
                hvA[2 * i]     = __hip_atomic_load(&c2x[i * 512 + tid * 2],
                                    __ATOMIC_RELAXED, __HIP_MEMORY_SCOPE_AGENT);
                hvA[2 * i + 1] = __hip_atomic_load(&c2x[i * 512 + tid * 2 + 1],
                                    __ATOMIC_RELAXED, __HIP_MEMORY_SCOPE_AGENT);
            }
        }
    }

    // ---- epilogue: dump rep registers (unique owner per (seq,unit))
    if (gate == 0) {
        repg[(size_t)(seq_base + w)     * H + rg * 16 + qlane] = r0;
        repg[(size_t)(seq_base + w + 4) * H + rg * 16 + qlane] = r1;
    }
}

// ---------------- final: rep mean + logits ----------------
__global__ __launch_bounds__(256) void lstm_final(
    const float* __restrict__ ws,
    const int* __restrict__ mask,
    const float* __restrict__ Wfc, const float* __restrict__ bfc,
    float* __restrict__ out)
{
    __shared__ float sred[256];
    __shared__ float srep[H];
    int s = blockIdx.x, tid = threadIdx.x;

    float dsum = 0.f;
    for (int i = tid; i < L; i += 256) dsum += (mask[(size_t)s * L + i] != 0) ? 1.f : 0.f;
    sred[tid] = dsum; __syncthreads();
    for (int off = 128; off > 0; off >>= 1) {
        if (tid < off) sred[tid] += sred[tid + off];
        __syncthreads();
    }
    float denom = fmaxf(sred[0], 1e-9f);
    __syncthreads();

    const float* repa = ws + OFF_REP + (size_t)s * H;
    for (int i = tid; i < H; i += 256) {
        float r = repa[i] / denom;
        srep[i] = r;
        out[128 + (size_t)s * H + i] = r;
    }
    __syncthreads();

    for (int c = 0; c < 2; ++c) {
        float d = 0.f;
        for (int i = tid; i < H; i += 256) d += srep[i] * Wfc[(size_t)c * H + i];
        sred[tid] = d; __syncthreads();
        for (int off = 128; off > 0; off >>= 1) {
            if (tid < off) sred[tid] += sred[tid + off];
            __syncthreads();
        }
        if (tid == 0) out[(size_t)s * 2 + c] = sred[0] + bfc[c];
        __syncthreads();
    }
}

// ---------------- host ----------------
extern "C" void kernel_launch(void* const* d_in, const int* in_sizes, int n_in,
                              void* d_out, int out_size, void* d_ws, size_t ws_size,
                              hipStream_t stream)
{
    const int*   x     = (const int*)d_in[0];
    const int*   mask  = (const int*)d_in[1];
    const float* embed = (const float*)d_in[2];
    const float* Wf = (const float*)d_in[3];  const float* bf = (const float*)d_in[4];
    const float* Wi = (const float*)d_in[5];  const float* bi = (const float*)d_in[6];
    const float* Wc = (const float*)d_in[7];  const float* bc = (const float*)d_in[8];
    const float* Wo = (const float*)d_in[9];  const float* bo = (const float*)d_in[10];
    const float* Wfc = (const float*)d_in[11]; const float* bfc = (const float*)d_in[12];
    float* out = (float*)d_out;
    float* ws  = (float*)d_ws;

    if (ws_size < WS_FLOATS * sizeof(float)) {
        return; // leave output poisoned so the failure mode is unambiguous
    }

    prep_weights<<<256, 256, 0, stream>>>(Wf, Wi, Wc, Wo, bf, bi, bc, bo, ws);
    lstm_persist<<<256, 256, 0, stream>>>(ws, x, mask, embed);
    lstm_final<<<64, 256, 0, stream>>>(ws, mask, Wfc, bfc, out);
}